// Round 21
// baseline (219.216 us; speedup 1.0000x reference)
//
#include <hip/hip_runtime.h>
#include <hip/hip_bf16.h>
#include <cmath>

#define B_   2
#define T_   4096
#define E_   768
#define NH_  12
#define HS_  64
#define QKV_ROW (3 * E_)   // 2304
#define LSE_N (B_ * NH_ * T_)   // 98304
#define BTE   (B_ * T_ * E_)    // 6291456

typedef __attribute__((ext_vector_type(8))) short bf16x8;
typedef __attribute__((ext_vector_type(4))) float f32x4;

__device__ __forceinline__ unsigned short f2bf(float f) {
    __hip_bfloat16 h = __float2bfloat16(f);
    return __builtin_bit_cast(unsigned short, h);
}
__device__ __forceinline__ float bf2f(unsigned short s) {
    unsigned int u = (unsigned int)s << 16;
    return __builtin_bit_cast(float, u);
}

#define GLOAD16(gptr, lptr)                                             \
    __builtin_amdgcn_global_load_lds(                                   \
        (const __attribute__((address_space(1))) void*)(gptr),          \
        (__attribute__((address_space(3))) void*)(lptr), 16, 0, 0)

// ---------------------------------------------------------------------------
// Fused prep: cvt_x (blocks 0..3071) + transpose W_attn (..3503) + W_proj.
// ---------------------------------------------------------------------------
__global__ __launch_bounds__(256) void prep_kernel(
    const float* __restrict__ x, unsigned short* __restrict__ xb,
    const float* __restrict__ Wa, unsigned short* __restrict__ Wat,
    const float* __restrict__ Wp, unsigned short* __restrict__ Wpt)
{
    __shared__ float tile[64][65];
    const int bid = blockIdx.x;
    const int tid = threadIdx.x;
    if (bid < 3072) {
        const int i = (bid * 256 + tid) * 8;
        const float4 v0 = *(const float4*)&x[i];
        const float4 v1 = *(const float4*)&x[i + 4];
        unsigned short o[8];
        o[0] = f2bf(v0.x); o[1] = f2bf(v0.y); o[2] = f2bf(v0.z); o[3] = f2bf(v0.w);
        o[4] = f2bf(v1.x); o[5] = f2bf(v1.y); o[6] = f2bf(v1.z); o[7] = f2bf(v1.w);
        *(int4*)&xb[i] = *(const int4*)o;
        return;
    }
    const float* W; unsigned short* Wt; int K, N, n0, k0;
    if (bid < 3504) {
        const int b2 = bid - 3072;            // 36 x 12
        W = Wa; Wt = Wat; K = E_; N = QKV_ROW;
        n0 = (b2 % 36) * 64; k0 = (b2 / 36) * 64;
    } else {
        const int b3 = bid - 3504;            // 12 x 12
        W = Wp; Wt = Wpt; K = E_; N = E_;
        n0 = (b3 % 12) * 64; k0 = (b3 / 12) * 64;
    }
    const int tc = tid & 15;
    const int tr = tid >> 4;
#pragma unroll
    for (int i = 0; i < 4; ++i) {
        const int k = tr + i * 16;
        const float4 v = *(const float4*)&W[(size_t)(k0 + k) * N + n0 + tc * 4];
        tile[k][tc * 4 + 0] = v.x; tile[k][tc * 4 + 1] = v.y;
        tile[k][tc * 4 + 2] = v.z; tile[k][tc * 4 + 3] = v.w;
    }
    __syncthreads();
    const int nr = tid >> 2;
    const int kc = (tid & 3) * 16;
    unsigned short o[16];
#pragma unroll
    for (int j = 0; j < 16; ++j) o[j] = f2bf(tile[kc + j][nr]);
    unsigned short* dst = &Wt[(size_t)(n0 + nr) * K + k0 + kc];
    *(int4*)dst       = *(const int4*)&o[0];
    *(int4*)(dst + 8) = *(const int4*)&o[8];
}

// ---------------------------------------------------------------------------
// GEMM (m97 structure): C[M,N] = A[M,K]bf16 @ Bt[N,K]bf16^T + bias.
// Operand-swapped MFMA epilogue (vectorized stores).
// ---------------------------------------------------------------------------
template<bool OUT_BF16, bool QSCALE>
__global__ __launch_bounds__(256) void gemm_bt_kernel(
    const unsigned short* __restrict__ A,   // [M][lda]
    const unsigned short* __restrict__ Bt,  // [N][K]
    const float* __restrict__ bias, void* __restrict__ Cout,
    int M, int N, int K, int lda)
{
    __shared__ __align__(16) unsigned short Als[128 * 64];
    __shared__ __align__(16) unsigned short Bls[128 * 64];

    const int tid  = threadIdx.x;
    const int m0   = blockIdx.y * 128;
    const int n0   = blockIdx.x * 128;
    const int w    = tid >> 6;
    const int lane = tid & 63;
    const int lr   = lane & 15;
    const int lk   = lane >> 4;
    const int wm   = (w >> 1) * 64;
    const int wn   = (w & 1) * 64;

    f32x4 acc[4][4];
#pragma unroll
    for (int i = 0; i < 4; ++i)
#pragma unroll
        for (int j = 0; j < 4; ++j) acc[i][j] = (f32x4){0.f, 0.f, 0.f, 0.f};

    for (int k0 = 0; k0 < K; k0 += 64) {
        __syncthreads();
#pragma unroll
        for (int c = 0; c < 4; ++c) {
            const int idx = c * 256 + tid;
            const int row = idx >> 3;
            const int g   = (tid & 7) ^ (row & 7);
            GLOAD16(&A[(size_t)(m0 + row) * lda + k0 + g * 8], &Als[idx * 8]);
        }
#pragma unroll
        for (int c = 0; c < 4; ++c) {
            const int idx = c * 256 + tid;
            const int row = idx >> 3;
            const int g   = (tid & 7) ^ (row & 7);
            GLOAD16(&Bt[(size_t)(n0 + row) * K + k0 + g * 8], &Bls[idx * 8]);
        }
        __syncthreads();

#pragma unroll
        for (int kk = 0; kk < 2; ++kk) {
            bf16x8 a[4], b[4];
            const int gp = ((kk * 4 + lk) ^ (lr & 7)) << 3;
#pragma unroll
            for (int i = 0; i < 4; ++i) {
                a[i] = *(const bf16x8*)&Als[(wm + i * 16 + lr) * 64 + gp];
                b[i] = *(const bf16x8*)&Bls[(wn + i * 16 + lr) * 64 + gp];
            }
#pragma unroll
            for (int i = 0; i < 4; ++i)
#pragma unroll
                for (int j = 0; j < 4; ++j)
                    acc[i][j] = __builtin_amdgcn_mfma_f32_16x16x32_bf16(
                        b[j], a[i], acc[i][j], 0, 0, 0);
        }
    }

    const float beta = 0.18033688011f;  // (1/sqrt(64)) * log2(e)
#pragma unroll
    for (int i = 0; i < 4; ++i) {
        const int row = m0 + wm + i * 16 + lr;
#pragma unroll
        for (int j = 0; j < 4; ++j) {
            const int nbase = n0 + wn + j * 16 + lk * 4;
            const float4 bv = *(const float4*)&bias[nbase];
            float v0 = acc[i][j][0] + bv.x;
            float v1 = acc[i][j][1] + bv.y;
            float v2 = acc[i][j][2] + bv.z;
            float v3 = acc[i][j][3] + bv.w;
            if (QSCALE && nbase < E_) {
                v0 *= beta; v1 *= beta; v2 *= beta; v3 *= beta;
            }
            if (OUT_BF16) {
                ushort4 o;
                o.x = f2bf(v0); o.y = f2bf(v1); o.z = f2bf(v2); o.w = f2bf(v3);
                *(ushort4*)&((unsigned short*)Cout)[(size_t)row * N + nbase] = o;
            } else {
                float4 o; o.x = v0; o.y = v1; o.z = v2; o.w = v3;
                *(float4*)&((float*)Cout)[(size_t)row * N + nbase] = o;
            }
        }
    }
}

// ---------------------------------------------------------------------------
// Flash attention (causal): paired q-tiles + 2-way kv parity split + XCD
// swizzle (T1). Fixed-scale softmax, in-register P, ones-row PV denominator.
// DOUBLE-BUFFERED reg-staged K/V: ONE barrier per kv-tile (covers RAW on
// buf[cur] and WAR on buf[cur^1]); ds_writes for tile j+2 overlap compute(j).
// ---------------------------------------------------------------------------
__global__ __launch_bounds__(256) void flash_kernel(
    const unsigned short* __restrict__ qkv,
    unsigned short* __restrict__ y_part,  // [2][B*T][E] bf16
    float* __restrict__ lsum)             // [2][B*NH*T] raw denominators
{
    __shared__ __align__(16) unsigned short K_lds[2][64][72];  // dbuf [kv][hs]
    __shared__ __align__(16) unsigned short Vt[2][64][72];     // dbuf [hs][kv] swz

    const int tid  = threadIdx.x;
    const int w    = tid >> 6;
    const int lane = tid & 63;
    const int lr   = lane & 15;
    const int lk   = lane >> 4;

    // XCD-aware decode: bid = (g%8) + 8*((g/8)*32 + qp), g = head*2 + z.
    const int bid  = blockIdx.x;
    const int xcd  = bid & 7;
    const int rr   = bid >> 3;
    const int g    = (rr >> 5) * 8 + xcd;   // 0..47
    const int head = g >> 1;                // 0..23
    const int z    = g & 1;
    const int qb_lo = rr & 31;              // 0..31
    const int b    = head / NH_;
    const int nh   = head % NH_;
    const int qb_hi = 63 - qb_lo;           // 32..63
    const int q0_lo = qb_lo * 64;
    const int q0_hi = qb_hi * 64;

    const unsigned short* qkv_b = qkv + (size_t)b * T_ * QKV_ROW;

    bf16x8 qf_lo[2], qf_hi[2];
    {
        const unsigned short* qrl =
            qkv_b + (size_t)(q0_lo + w * 16 + lr) * QKV_ROW + nh * HS_;
        qf_lo[0] = *(const bf16x8*)(qrl + lk * 8);
        qf_lo[1] = *(const bf16x8*)(qrl + 32 + lk * 8);
        const unsigned short* qrh =
            qkv_b + (size_t)(q0_hi + w * 16 + lr) * QKV_ROW + nh * HS_;
        qf_hi[0] = *(const bf16x8*)(qrh + lk * 8);
        qf_hi[1] = *(const bf16x8*)(qrh + 32 + lk * 8);
    }

    // ones A-row fragment: A[0][k] = 1, other rows 0
    bf16x8 af1;
    {
        const short one = (lr == 0) ? (short)0x3F80 : (short)0;
#pragma unroll
        for (int j = 0; j < 8; ++j) af1[j] = one;
    }

    f32x4 acc_lo[4], acc_hi[4];
    f32x4 accl_lo = (f32x4){0.f, 0.f, 0.f, 0.f};
    f32x4 accl_hi = (f32x4){0.f, 0.f, 0.f, 0.f};
#pragma unroll
    for (int i = 0; i < 4; ++i) {
        acc_lo[i] = (f32x4){0.f, 0.f, 0.f, 0.f};
        acc_hi[i] = (f32x4){0.f, 0.f, 0.f, 0.f};
    }

    const int sr = tid >> 2;          // staging row (kv)
    const int sc = (tid & 3) * 16;    // staging col base (hs)

    // fixed-scale softmax: P = exp2(s); mask only on diag tiles
    auto softmax_pack = [&](f32x4* st, int q0, int kv0, bool diag,
                            bf16x8& pf0, bf16x8& pf1) {
        const int tq = q0 + w * 16 + lr;
        if (diag) {
#pragma unroll
            for (int cb = 0; cb < 4; ++cb)
#pragma unroll
                for (int r = 0; r < 4; ++r) {
                    const int tk = kv0 + cb * 16 + lk * 4 + r;
                    if (tk > tq) st[cb][r] = -INFINITY;
                }
        }
#pragma unroll
        for (int r = 0; r < 4; ++r) {
            pf0[r]     = (short)f2bf(exp2f(st[0][r]));
            pf0[r + 4] = (short)f2bf(exp2f(st[1][r]));
            pf1[r]     = (short)f2bf(exp2f(st[2][r]));
            pf1[r + 4] = (short)f2bf(exp2f(st[3][r]));
        }
    };

    // T14 staging registers (tile in flight)
    int4 k01r, k23r, v01r, v23r;
    auto load_regs = [&](int j) {
        const unsigned short* krow =
            qkv_b + (size_t)(j * 64 + sr) * QKV_ROW + E_ + nh * HS_ + sc;
        const unsigned short* vrow = krow + E_;
        k01r = *(const int4*)krow;
        k23r = *(const int4*)(krow + 8);
        v01r = *(const int4*)vrow;
        v23r = *(const int4*)(vrow + 8);
    };
    // stage regs -> LDS buffer bi
    auto stage = [&](int bi) {
        *(int4*)&K_lds[bi][sr][sc]     = k01r;
        *(int4*)&K_lds[bi][sr][sc + 8] = k23r;
        const unsigned short* vs0 = (const unsigned short*)&v01r;
        const unsigned short* vs1 = (const unsigned short*)&v23r;
        const int kvhi = sr >> 3, kvlo = sr & 7;
#pragma unroll
        for (int i = 0; i < 8; ++i) {
            const int h = sc + i;
            Vt[bi][h][((kvhi ^ (h >> 3)) << 3) + kvlo] = vs0[i];
        }
#pragma unroll
        for (int i = 0; i < 8; ++i) {
            const int h = sc + 8 + i;
            Vt[bi][h][((kvhi ^ (h >> 3)) << 3) + kvlo] = vs1[i];
        }
    };

    // prologue: stage tile z into buf0, prefetch tile z+2 to regs
    load_regs(z);
    stage(0);
    if (z + 2 <= qb_hi) load_regs(z + 2);

    int cur = 0;
    for (int j = z; j <= qb_hi; j += 2, cur ^= 1) {
        const int kv0 = j * 64;
        const bool do_lo = (j <= qb_lo);
        __syncthreads();   // buf[cur] writes visible; buf[cur^1] reads done
        const int jn = j + 2;
        if (jn <= qb_hi) {
            stage(cur ^ 1);                       // overlaps with compute(j)
            if (jn + 2 <= qb_hi) load_regs(jn + 2);
        }

        bf16x8 kf[4][2];
#pragma unroll
        for (int cb = 0; cb < 4; ++cb)
#pragma unroll
            for (int ks = 0; ks < 2; ++ks)
                kf[cb][ks] = *(const bf16x8*)&K_lds[cur][cb * 16 + lr][ks * 32 + lk * 8];

        bf16x8 vf[4][2];
#pragma unroll
        for (int cb2 = 0; cb2 < 4; ++cb2) {
            const int row = cb2 * 16 + lr;
            const int sw  = row >> 3;
#pragma unroll
            for (int ks = 0; ks < 2; ++ks) {
                const int cA = ((4 * ks + (lk >> 1)) ^ sw);
                const int cB = ((4 * ks + 2 + (lk >> 1)) ^ sw);
                const int off = 4 * (lk & 1);
                ushort4 a = *(const ushort4*)&Vt[cur][row][cA * 8 + off];
                ushort4 bq = *(const ushort4*)&Vt[cur][row][cB * 8 + off];
                bf16x8 v;
                v[0] = (short)a.x;  v[1] = (short)a.y;
                v[2] = (short)a.z;  v[3] = (short)a.w;
                v[4] = (short)bq.x; v[5] = (short)bq.y;
                v[6] = (short)bq.z; v[7] = (short)bq.w;
                vf[cb2][ks] = v;
            }
        }

        f32x4 st_hi[4], st_lo[4];
        __builtin_amdgcn_s_setprio(1);
#pragma unroll
        for (int cb = 0; cb < 4; ++cb) {
            st_hi[cb] = (f32x4){0.f, 0.f, 0.f, 0.f};
            st_hi[cb] = __builtin_amdgcn_mfma_f32_16x16x32_bf16(kf[cb][0], qf_hi[0], st_hi[cb], 0, 0, 0);
            st_hi[cb] = __builtin_amdgcn_mfma_f32_16x16x32_bf16(kf[cb][1], qf_hi[1], st_hi[cb], 0, 0, 0);
        }
        if (do_lo) {
#pragma unroll
            for (int cb = 0; cb < 4; ++cb) {
                st_lo[cb] = (f32x4){0.f, 0.f, 0.f, 0.f};
                st_lo[cb] = __builtin_amdgcn_mfma_f32_16x16x32_bf16(kf[cb][0], qf_lo[0], st_lo[cb], 0, 0, 0);
                st_lo[cb] = __builtin_amdgcn_mfma_f32_16x16x32_bf16(kf[cb][1], qf_lo[1], st_lo[cb], 0, 0, 0);
            }
        }
        __builtin_amdgcn_s_setprio(0);

        bf16x8 pf0, pf1;
        softmax_pack(st_hi, q0_hi, kv0, j == qb_hi, pf0, pf1);
        __builtin_amdgcn_s_setprio(1);
#pragma unroll
        for (int cb2 = 0; cb2 < 4; ++cb2) {
            acc_hi[cb2] = __builtin_amdgcn_mfma_f32_16x16x32_bf16(vf[cb2][0], pf0, acc_hi[cb2], 0, 0, 0);
            acc_hi[cb2] = __builtin_amdgcn_mfma_f32_16x16x32_bf16(vf[cb2][1], pf1, acc_hi[cb2], 0, 0, 0);
        }
        accl_hi = __builtin_amdgcn_mfma_f32_16x16x32_bf16(af1, pf0, accl_hi, 0, 0, 0);
        accl_hi = __builtin_amdgcn_mfma_f32_16x16x32_bf16(af1, pf1, accl_hi, 0, 0, 0);
        __builtin_amdgcn_s_setprio(0);

        if (do_lo) {
            softmax_pack(st_lo, q0_lo, kv0, j == qb_lo, pf0, pf1);
            __builtin_amdgcn_s_setprio(1);
#pragma unroll
            for (int cb2 = 0; cb2 < 4; ++cb2) {
                acc_lo[cb2] = __builtin_amdgcn_mfma_f32_16x16x32_bf16(vf[cb2][0], pf0, acc_lo[cb2], 0, 0, 0);
                acc_lo[cb2] = __builtin_amdgcn_mfma_f32_16x16x32_bf16(vf[cb2][1], pf1, acc_lo[cb2], 0, 0, 0);
            }
            accl_lo = __builtin_amdgcn_mfma_f32_16x16x32_bf16(af1, pf0, accl_lo, 0, 0, 0);
            accl_lo = __builtin_amdgcn_mfma_f32_16x16x32_bf16(af1, pf1, accl_lo, 0, 0, 0);
            __builtin_amdgcn_s_setprio(0);
        }
    }

    {
        const float lh = __shfl(accl_hi[0], lr);
        const float ll = __shfl(accl_lo[0], lr);
        unsigned short* yp = y_part + (size_t)z * BTE;
        const float li_hi = (lh > 0.f) ? 1.0f / lh : 0.f;
        const float li_lo = (ll > 0.f) ? 1.0f / ll : 0.f;
        const int tq_hi = q0_hi + w * 16 + lr;
        const int tq_lo = q0_lo + w * 16 + lr;
        unsigned short* yh = &yp[(size_t)(b * T_ + tq_hi) * E_ + nh * HS_];
        unsigned short* yl = &yp[(size_t)(b * T_ + tq_lo) * E_ + nh * HS_];
#pragma unroll
        for (int cb2 = 0; cb2 < 4; ++cb2) {
            ushort4 oh, ol;
            oh.x = f2bf(acc_hi[cb2][0] * li_hi); oh.y = f2bf(acc_hi[cb2][1] * li_hi);
            oh.z = f2bf(acc_hi[cb2][2] * li_hi); oh.w = f2bf(acc_hi[cb2][3] * li_hi);
            ol.x = f2bf(acc_lo[cb2][0] * li_lo); ol.y = f2bf(acc_lo[cb2][1] * li_lo);
            ol.z = f2bf(acc_lo[cb2][2] * li_lo); ol.w = f2bf(acc_lo[cb2][3] * li_lo);
            *(ushort4*)&yh[cb2 * 16 + lk * 4] = oh;
            *(ushort4*)&yl[cb2 * 16 + lk * 4] = ol;
        }
        if (lk == 0) {
            float* lz = lsum + (size_t)z * LSE_N + (size_t)head * T_;
            lz[tq_hi] = lh;
            lz[tq_lo] = ll;
        }
    }
}

// ---------------------------------------------------------------------------
// Merge the two kv-split partials -> bf16 y (contiguous, x_bf16 region).
// ---------------------------------------------------------------------------
__global__ __launch_bounds__(256) void merge_kernel(
    const unsigned short* __restrict__ y_part,  // [2][B*T][E] bf16
    const float* __restrict__ lsum,             // [2][B*NH*T]
    unsigned short* __restrict__ y)             // [B*T][E] bf16
{
    const int i  = blockIdx.x * 256 + threadIdx.x;
    const int e0 = i * 8;
    const int row = e0 / E_;
    const int e   = e0 - row * E_;
    const int nh  = e >> 6;
    const int lidx = ((row >> 12) * NH_ + nh) * T_ + (row & (T_ - 1));
    const float l0 = lsum[lidx];
    const float l1 = lsum[LSE_N + lidx];
    const float inv = 1.0f / (l0 + l1);
    const float w0 = l0 * inv, w1 = l1 * inv;
    bf16x8 p0 = *(const bf16x8*)&y_part[e0];
    bf16x8 p1 = *(const bf16x8*)&y_part[(size_t)BTE + e0];
    ushort4 oa, ob;
    unsigned short o[8];
#pragma unroll
    for (int jj = 0; jj < 8; ++jj)
        o[jj] = f2bf(w0 * bf2f((unsigned short)p0[jj]) +
                     w1 * bf2f((unsigned short)p1[jj]));
    oa.x = o[0]; oa.y = o[1]; oa.z = o[2]; oa.w = o[3];
    ob.x = o[4]; ob.y = o[5]; ob.z = o[6]; ob.w = o[7];
    unsigned short* dst = &y[e0];
    *(ushort4*)dst = oa;
    *(ushort4*)(dst + 4) = ob;
}

// ---------------------------------------------------------------------------
extern "C" void kernel_launch(void* const* d_in, const int* in_sizes, int n_in,
                              void* d_out, int out_size, void* d_ws, size_t ws_size,
                              hipStream_t stream)
{
    const float* x      = (const float*)d_in[0];
    const float* W_attn = (const float*)d_in[1];
    const float* b_attn = (const float*)d_in[2];
    const float* W_proj = (const float*)d_in[3];
    const float* b_proj = (const float*)d_in[4];
    float* out = (float*)d_out;

    char* ws = (char*)d_ws;
    unsigned short* qkv_ws  = (unsigned short*)ws;                    // 37,748,736 B
    float*          lsum_ws = (float*)(ws + 37748736);                //    786,432 B
    unsigned short* x_bf16  = (unsigned short*)(ws + 38535168);       // 12,582,912 B
    unsigned short* wt_attn = (unsigned short*)(ws + 51118080);       //  3,538,944 B
    unsigned short* wt_proj = (unsigned short*)(ws + 54657024);       //  1,179,648 B
    unsigned short* y_part   = (unsigned short*)d_out;                // bf16 [2][8192][768]
    unsigned short* y_merged = x_bf16;   // dead after gemm1

    dim3 blk(256);

    // 0) fused prep: cvt_x + both weight transposes in one dispatch
    prep_kernel<<<dim3(3072 + 432 + 144), blk, 0, stream>>>(
        x, x_bf16, W_attn, wt_attn, W_proj, wt_proj);

    // 1) qkv = x @ W_attn + b_attn  (Q cols pre-scaled by beta) -> bf16
    gemm_bt_kernel<true, true><<<dim3(QKV_ROW / 128, (B_ * T_) / 128), blk, 0, stream>>>(
        x_bf16, wt_attn, b_attn, (void*)qkv_ws, B_ * T_, QKV_ROW, E_, E_);

    // 2) flash attention (XCD-swizzled 1D grid, dbuf single-barrier) -> partials
    flash_kernel<<<dim3((T_ / 128) * B_ * NH_ * 2), blk, 0, stream>>>(
        qkv_ws, y_part, lsum_ws);

    // 3) merge partials -> contiguous bf16 y
    merge_kernel<<<dim3(BTE / 8 / 256), blk, 0, stream>>>(y_part, lsum_ws, y_merged);

    // 4) out = y @ W_proj + b_proj -> fp32
    gemm_bt_kernel<false, false><<<dim3(E_ / 128, (B_ * T_) / 128), blk, 0, stream>>>(
        y_merged, wt_proj, b_proj, (void*)out, B_ * T_, E_, E_, E_);
}

// Round 22
// 209.404 us; speedup vs baseline: 1.0469x; 1.0469x over previous
//
#include <hip/hip_runtime.h>
#include <hip/hip_bf16.h>
#include <cmath>

#define B_   2
#define T_   4096
#define E_   768
#define NH_  12
#define HS_  64
#define QKV_ROW (3 * E_)   // 2304
#define LSE_N (B_ * NH_ * T_)   // 98304
#define BTE   (B_ * T_ * E_)    // 6291456

typedef __attribute__((ext_vector_type(8))) short bf16x8;
typedef __attribute__((ext_vector_type(4))) float f32x4;

__device__ __forceinline__ unsigned short f2bf(float f) {
    __hip_bfloat16 h = __float2bfloat16(f);
    return __builtin_bit_cast(unsigned short, h);
}
__device__ __forceinline__ float bf2f(unsigned short s) {
    unsigned int u = (unsigned int)s << 16;
    return __builtin_bit_cast(float, u);
}

#define GLOAD16(gptr, lptr)                                             \
    __builtin_amdgcn_global_load_lds(                                   \
        (const __attribute__((address_space(1))) void*)(gptr),          \
        (__attribute__((address_space(3))) void*)(lptr), 16, 0, 0)

// ---------------------------------------------------------------------------
// Fused prep: cvt_x (blocks 0..3071) + transpose W_attn (..3503) + W_proj.
// ---------------------------------------------------------------------------
__global__ __launch_bounds__(256) void prep_kernel(
    const float* __restrict__ x, unsigned short* __restrict__ xb,
    const float* __restrict__ Wa, unsigned short* __restrict__ Wat,
    const float* __restrict__ Wp, unsigned short* __restrict__ Wpt)
{
    __shared__ float tile[64][65];
    const int bid = blockIdx.x;
    const int tid = threadIdx.x;
    if (bid < 3072) {
        const int i = (bid * 256 + tid) * 8;
        const float4 v0 = *(const float4*)&x[i];
        const float4 v1 = *(const float4*)&x[i + 4];
        unsigned short o[8];
        o[0] = f2bf(v0.x); o[1] = f2bf(v0.y); o[2] = f2bf(v0.z); o[3] = f2bf(v0.w);
        o[4] = f2bf(v1.x); o[5] = f2bf(v1.y); o[6] = f2bf(v1.z); o[7] = f2bf(v1.w);
        *(int4*)&xb[i] = *(const int4*)o;
        return;
    }
    const float* W; unsigned short* Wt; int K, N, n0, k0;
    if (bid < 3504) {
        const int b2 = bid - 3072;            // 36 x 12
        W = Wa; Wt = Wat; K = E_; N = QKV_ROW;
        n0 = (b2 % 36) * 64; k0 = (b2 / 36) * 64;
    } else {
        const int b3 = bid - 3504;            // 12 x 12
        W = Wp; Wt = Wpt; K = E_; N = E_;
        n0 = (b3 % 12) * 64; k0 = (b3 / 12) * 64;
    }
    const int tc = tid & 15;
    const int tr = tid >> 4;
#pragma unroll
    for (int i = 0; i < 4; ++i) {
        const int k = tr + i * 16;
        const float4 v = *(const float4*)&W[(size_t)(k0 + k) * N + n0 + tc * 4];
        tile[k][tc * 4 + 0] = v.x; tile[k][tc * 4 + 1] = v.y;
        tile[k][tc * 4 + 2] = v.z; tile[k][tc * 4 + 3] = v.w;
    }
    __syncthreads();
    const int nr = tid >> 2;
    const int kc = (tid & 3) * 16;
    unsigned short o[16];
#pragma unroll
    for (int j = 0; j < 16; ++j) o[j] = f2bf(tile[kc + j][nr]);
    unsigned short* dst = &Wt[(size_t)(n0 + nr) * K + k0 + kc];
    *(int4*)dst       = *(const int4*)&o[0];
    *(int4*)(dst + 8) = *(const int4*)&o[8];
}

// ---------------------------------------------------------------------------
// GEMM (m97 structure): C[M,N] = A[M,K]bf16 @ Bt[N,K]bf16^T + bias.
// Operand-swapped MFMA epilogue (vectorized stores).
// ---------------------------------------------------------------------------
template<bool OUT_BF16, bool QSCALE>
__global__ __launch_bounds__(256) void gemm_bt_kernel(
    const unsigned short* __restrict__ A,   // [M][lda]
    const unsigned short* __restrict__ Bt,  // [N][K]
    const float* __restrict__ bias, void* __restrict__ Cout,
    int M, int N, int K, int lda)
{
    __shared__ __align__(16) unsigned short Als[128 * 64];
    __shared__ __align__(16) unsigned short Bls[128 * 64];

    const int tid  = threadIdx.x;
    const int m0   = blockIdx.y * 128;
    const int n0   = blockIdx.x * 128;
    const int w    = tid >> 6;
    const int lane = tid & 63;
    const int lr   = lane & 15;
    const int lk   = lane >> 4;
    const int wm   = (w >> 1) * 64;
    const int wn   = (w & 1) * 64;

    f32x4 acc[4][4];
#pragma unroll
    for (int i = 0; i < 4; ++i)
#pragma unroll
        for (int j = 0; j < 4; ++j) acc[i][j] = (f32x4){0.f, 0.f, 0.f, 0.f};

    for (int k0 = 0; k0 < K; k0 += 64) {
        __syncthreads();
#pragma unroll
        for (int c = 0; c < 4; ++c) {
            const int idx = c * 256 + tid;
            const int row = idx >> 3;
            const int g   = (tid & 7) ^ (row & 7);
            GLOAD16(&A[(size_t)(m0 + row) * lda + k0 + g * 8], &Als[idx * 8]);
        }
#pragma unroll
        for (int c = 0; c < 4; ++c) {
            const int idx = c * 256 + tid;
            const int row = idx >> 3;
            const int g   = (tid & 7) ^ (row & 7);
            GLOAD16(&Bt[(size_t)(n0 + row) * K + k0 + g * 8], &Bls[idx * 8]);
        }
        __syncthreads();

#pragma unroll
        for (int kk = 0; kk < 2; ++kk) {
            bf16x8 a[4], b[4];
            const int gp = ((kk * 4 + lk) ^ (lr & 7)) << 3;
#pragma unroll
            for (int i = 0; i < 4; ++i) {
                a[i] = *(const bf16x8*)&Als[(wm + i * 16 + lr) * 64 + gp];
                b[i] = *(const bf16x8*)&Bls[(wn + i * 16 + lr) * 64 + gp];
            }
#pragma unroll
            for (int i = 0; i < 4; ++i)
#pragma unroll
                for (int j = 0; j < 4; ++j)
                    acc[i][j] = __builtin_amdgcn_mfma_f32_16x16x32_bf16(
                        b[j], a[i], acc[i][j], 0, 0, 0);
        }
    }

    const float beta = 0.18033688011f;  // (1/sqrt(64)) * log2(e)
#pragma unroll
    for (int i = 0; i < 4; ++i) {
        const int row = m0 + wm + i * 16 + lr;
#pragma unroll
        for (int j = 0; j < 4; ++j) {
            const int nbase = n0 + wn + j * 16 + lk * 4;
            const float4 bv = *(const float4*)&bias[nbase];
            float v0 = acc[i][j][0] + bv.x;
            float v1 = acc[i][j][1] + bv.y;
            float v2 = acc[i][j][2] + bv.z;
            float v3 = acc[i][j][3] + bv.w;
            if (QSCALE && nbase < E_) {
                v0 *= beta; v1 *= beta; v2 *= beta; v3 *= beta;
            }
            if (OUT_BF16) {
                ushort4 o;
                o.x = f2bf(v0); o.y = f2bf(v1); o.z = f2bf(v2); o.w = f2bf(v3);
                *(ushort4*)&((unsigned short*)Cout)[(size_t)row * N + nbase] = o;
            } else {
                float4 o; o.x = v0; o.y = v1; o.z = v2; o.w = v3;
                *(float4*)&((float*)Cout)[(size_t)row * N + nbase] = o;
            }
        }
    }
}

// ---------------------------------------------------------------------------
// Flash attention (causal): paired q-tiles + 2-way kv parity split + XCD
// swizzle (T1). Fixed-scale softmax, reg-staged K+V (T14), in-register P,
// ones-row PV denominator on matrix pipe. Two-barrier single-buffer loop —
// measured optimum (dbuf/1-barrier, gload_lds, occupancy forcing all lost).
// ---------------------------------------------------------------------------
__global__ __launch_bounds__(256) void flash_kernel(
    const unsigned short* __restrict__ qkv,
    unsigned short* __restrict__ y_part,  // [2][B*T][E] bf16
    float* __restrict__ lsum)             // [2][B*NH*T] raw denominators
{
    __shared__ __align__(16) unsigned short K_lds[64][72];    // [kv][hs]
    __shared__ __align__(16) unsigned short Vt[64][72];       // [hs][kv] swizzled

    const int tid  = threadIdx.x;
    const int w    = tid >> 6;
    const int lane = tid & 63;
    const int lr   = lane & 15;
    const int lk   = lane >> 4;

    // XCD-aware decode: bid = (g%8) + 8*((g/8)*32 + qp), g = head*2 + z.
    const int bid  = blockIdx.x;
    const int xcd  = bid & 7;
    const int rr   = bid >> 3;
    const int g    = (rr >> 5) * 8 + xcd;   // 0..47
    const int head = g >> 1;                // 0..23
    const int z    = g & 1;
    const int qb_lo = rr & 31;              // 0..31
    const int b    = head / NH_;
    const int nh   = head % NH_;
    const int qb_hi = 63 - qb_lo;           // 32..63
    const int q0_lo = qb_lo * 64;
    const int q0_hi = qb_hi * 64;

    const unsigned short* qkv_b = qkv + (size_t)b * T_ * QKV_ROW;

    bf16x8 qf_lo[2], qf_hi[2];
    {
        const unsigned short* qrl =
            qkv_b + (size_t)(q0_lo + w * 16 + lr) * QKV_ROW + nh * HS_;
        qf_lo[0] = *(const bf16x8*)(qrl + lk * 8);
        qf_lo[1] = *(const bf16x8*)(qrl + 32 + lk * 8);
        const unsigned short* qrh =
            qkv_b + (size_t)(q0_hi + w * 16 + lr) * QKV_ROW + nh * HS_;
        qf_hi[0] = *(const bf16x8*)(qrh + lk * 8);
        qf_hi[1] = *(const bf16x8*)(qrh + 32 + lk * 8);
    }

    // ones A-row fragment: A[0][k] = 1, other rows 0
    bf16x8 af1;
    {
        const short one = (lr == 0) ? (short)0x3F80 : (short)0;
#pragma unroll
        for (int j = 0; j < 8; ++j) af1[j] = one;
    }

    f32x4 acc_lo[4], acc_hi[4];
    f32x4 accl_lo = (f32x4){0.f, 0.f, 0.f, 0.f};
    f32x4 accl_hi = (f32x4){0.f, 0.f, 0.f, 0.f};
#pragma unroll
    for (int i = 0; i < 4; ++i) {
        acc_lo[i] = (f32x4){0.f, 0.f, 0.f, 0.f};
        acc_hi[i] = (f32x4){0.f, 0.f, 0.f, 0.f};
    }

    const int sr = tid >> 2;          // staging row (kv)
    const int sc = (tid & 3) * 16;    // staging col base (hs)

    // fixed-scale softmax: P = exp2(s); mask only on diag tiles
    auto softmax_pack = [&](f32x4* st, int q0, int kv0, bool diag,
                            bf16x8& pf0, bf16x8& pf1) {
        const int tq = q0 + w * 16 + lr;
        if (diag) {
#pragma unroll
            for (int cb = 0; cb < 4; ++cb)
#pragma unroll
                for (int r = 0; r < 4; ++r) {
                    const int tk = kv0 + cb * 16 + lk * 4 + r;
                    if (tk > tq) st[cb][r] = -INFINITY;
                }
        }
#pragma unroll
        for (int r = 0; r < 4; ++r) {
            pf0[r]     = (short)f2bf(exp2f(st[0][r]));
            pf0[r + 4] = (short)f2bf(exp2f(st[1][r]));
            pf1[r]     = (short)f2bf(exp2f(st[2][r]));
            pf1[r + 4] = (short)f2bf(exp2f(st[3][r]));
        }
    };

    // T14 staging registers (next tile in flight)
    int4 k01r, k23r, v01r, v23r;
    auto load_regs = [&](int j) {
        const unsigned short* krow =
            qkv_b + (size_t)(j * 64 + sr) * QKV_ROW + E_ + nh * HS_ + sc;
        const unsigned short* vrow = krow + E_;
        k01r = *(const int4*)krow;
        k23r = *(const int4*)(krow + 8);
        v01r = *(const int4*)vrow;
        v23r = *(const int4*)(vrow + 8);
    };

    load_regs(z);
    for (int j = z; j <= qb_hi; ) {
        const int kv0 = j * 64;
        const bool do_lo = (j <= qb_lo);
        __syncthreads();
        {
            *(int4*)&K_lds[sr][sc]     = k01r;
            *(int4*)&K_lds[sr][sc + 8] = k23r;
            const unsigned short* vs0 = (const unsigned short*)&v01r;
            const unsigned short* vs1 = (const unsigned short*)&v23r;
            const int kvhi = sr >> 3, kvlo = sr & 7;
#pragma unroll
            for (int i = 0; i < 8; ++i) {
                const int h = sc + i;
                Vt[h][((kvhi ^ (h >> 3)) << 3) + kvlo] = vs0[i];
            }
#pragma unroll
            for (int i = 0; i < 8; ++i) {
                const int h = sc + 8 + i;
                Vt[h][((kvhi ^ (h >> 3)) << 3) + kvlo] = vs1[i];
            }
        }
        __syncthreads();

        const int jn = j + 2;
        if (jn <= qb_hi) load_regs(jn);

        bf16x8 kf[4][2];
#pragma unroll
        for (int cb = 0; cb < 4; ++cb)
#pragma unroll
            for (int ks = 0; ks < 2; ++ks)
                kf[cb][ks] = *(const bf16x8*)&K_lds[cb * 16 + lr][ks * 32 + lk * 8];

        bf16x8 vf[4][2];
#pragma unroll
        for (int cb2 = 0; cb2 < 4; ++cb2) {
            const int row = cb2 * 16 + lr;
            const int sw  = row >> 3;
#pragma unroll
            for (int ks = 0; ks < 2; ++ks) {
                const int cA = ((4 * ks + (lk >> 1)) ^ sw);
                const int cB = ((4 * ks + 2 + (lk >> 1)) ^ sw);
                const int off = 4 * (lk & 1);
                ushort4 a = *(const ushort4*)&Vt[row][cA * 8 + off];
                ushort4 bq = *(const ushort4*)&Vt[row][cB * 8 + off];
                bf16x8 v;
                v[0] = (short)a.x;  v[1] = (short)a.y;
                v[2] = (short)a.z;  v[3] = (short)a.w;
                v[4] = (short)bq.x; v[5] = (short)bq.y;
                v[6] = (short)bq.z; v[7] = (short)bq.w;
                vf[cb2][ks] = v;
            }
        }

        f32x4 st_hi[4], st_lo[4];
        __builtin_amdgcn_s_setprio(1);
#pragma unroll
        for (int cb = 0; cb < 4; ++cb) {
            st_hi[cb] = (f32x4){0.f, 0.f, 0.f, 0.f};
            st_hi[cb] = __builtin_amdgcn_mfma_f32_16x16x32_bf16(kf[cb][0], qf_hi[0], st_hi[cb], 0, 0, 0);
            st_hi[cb] = __builtin_amdgcn_mfma_f32_16x16x32_bf16(kf[cb][1], qf_hi[1], st_hi[cb], 0, 0, 0);
        }
        if (do_lo) {
#pragma unroll
            for (int cb = 0; cb < 4; ++cb) {
                st_lo[cb] = (f32x4){0.f, 0.f, 0.f, 0.f};
                st_lo[cb] = __builtin_amdgcn_mfma_f32_16x16x32_bf16(kf[cb][0], qf_lo[0], st_lo[cb], 0, 0, 0);
                st_lo[cb] = __builtin_amdgcn_mfma_f32_16x16x32_bf16(kf[cb][1], qf_lo[1], st_lo[cb], 0, 0, 0);
            }
        }
        __builtin_amdgcn_s_setprio(0);

        bf16x8 pf0, pf1;
        softmax_pack(st_hi, q0_hi, kv0, j == qb_hi, pf0, pf1);
        __builtin_amdgcn_s_setprio(1);
#pragma unroll
        for (int cb2 = 0; cb2 < 4; ++cb2) {
            acc_hi[cb2] = __builtin_amdgcn_mfma_f32_16x16x32_bf16(vf[cb2][0], pf0, acc_hi[cb2], 0, 0, 0);
            acc_hi[cb2] = __builtin_amdgcn_mfma_f32_16x16x32_bf16(vf[cb2][1], pf1, acc_hi[cb2], 0, 0, 0);
        }
        accl_hi = __builtin_amdgcn_mfma_f32_16x16x32_bf16(af1, pf0, accl_hi, 0, 0, 0);
        accl_hi = __builtin_amdgcn_mfma_f32_16x16x32_bf16(af1, pf1, accl_hi, 0, 0, 0);
        __builtin_amdgcn_s_setprio(0);

        if (do_lo) {
            softmax_pack(st_lo, q0_lo, kv0, j == qb_lo, pf0, pf1);
            __builtin_amdgcn_s_setprio(1);
#pragma unroll
            for (int cb2 = 0; cb2 < 4; ++cb2) {
                acc_lo[cb2] = __builtin_amdgcn_mfma_f32_16x16x32_bf16(vf[cb2][0], pf0, acc_lo[cb2], 0, 0, 0);
                acc_lo[cb2] = __builtin_amdgcn_mfma_f32_16x16x32_bf16(vf[cb2][1], pf1, acc_lo[cb2], 0, 0, 0);
            }
            accl_lo = __builtin_amdgcn_mfma_f32_16x16x32_bf16(af1, pf0, accl_lo, 0, 0, 0);
            accl_lo = __builtin_amdgcn_mfma_f32_16x16x32_bf16(af1, pf1, accl_lo, 0, 0, 0);
            __builtin_amdgcn_s_setprio(0);
        }
        j = jn;
    }

    {
        const float lh = __shfl(accl_hi[0], lr);
        const float ll = __shfl(accl_lo[0], lr);
        unsigned short* yp = y_part + (size_t)z * BTE;
        const float li_hi = (lh > 0.f) ? 1.0f / lh : 0.f;
        const float li_lo = (ll > 0.f) ? 1.0f / ll : 0.f;
        const int tq_hi = q0_hi + w * 16 + lr;
        const int tq_lo = q0_lo + w * 16 + lr;
        unsigned short* yh = &yp[(size_t)(b * T_ + tq_hi) * E_ + nh * HS_];
        unsigned short* yl = &yp[(size_t)(b * T_ + tq_lo) * E_ + nh * HS_];
#pragma unroll
        for (int cb2 = 0; cb2 < 4; ++cb2) {
            ushort4 oh, ol;
            oh.x = f2bf(acc_hi[cb2][0] * li_hi); oh.y = f2bf(acc_hi[cb2][1] * li_hi);
            oh.z = f2bf(acc_hi[cb2][2] * li_hi); oh.w = f2bf(acc_hi[cb2][3] * li_hi);
            ol.x = f2bf(acc_lo[cb2][0] * li_lo); ol.y = f2bf(acc_lo[cb2][1] * li_lo);
            ol.z = f2bf(acc_lo[cb2][2] * li_lo); ol.w = f2bf(acc_lo[cb2][3] * li_lo);
            *(ushort4*)&yh[cb2 * 16 + lk * 4] = oh;
            *(ushort4*)&yl[cb2 * 16 + lk * 4] = ol;
        }
        if (lk == 0) {
            float* lz = lsum + (size_t)z * LSE_N + (size_t)head * T_;
            lz[tq_hi] = lh;
            lz[tq_lo] = ll;
        }
    }
}

// ---------------------------------------------------------------------------
// Merge the two kv-split partials -> bf16 y (contiguous, x_bf16 region).
// ---------------------------------------------------------------------------
__global__ __launch_bounds__(256) void merge_kernel(
    const unsigned short* __restrict__ y_part,  // [2][B*T][E] bf16
    const float* __restrict__ lsum,             // [2][B*NH*T]
    unsigned short* __restrict__ y)             // [B*T][E] bf16
{
    const int i  = blockIdx.x * 256 + threadIdx.x;
    const int e0 = i * 8;
    const int row = e0 / E_;
    const int e   = e0 - row * E_;
    const int nh  = e >> 6;
    const int lidx = ((row >> 12) * NH_ + nh) * T_ + (row & (T_ - 1));
    const float l0 = lsum[lidx];
    const float l1 = lsum[LSE_N + lidx];
    const float inv = 1.0f / (l0 + l1);
    const float w0 = l0 * inv, w1 = l1 * inv;
    bf16x8 p0 = *(const bf16x8*)&y_part[e0];
    bf16x8 p1 = *(const bf16x8*)&y_part[(size_t)BTE + e0];
    ushort4 oa, ob;
    unsigned short o[8];
#pragma unroll
    for (int jj = 0; jj < 8; ++jj)
        o[jj] = f2bf(w0 * bf2f((unsigned short)p0[jj]) +
                     w1 * bf2f((unsigned short)p1[jj]));
    oa.x = o[0]; oa.y = o[1]; oa.z = o[2]; oa.w = o[3];
    ob.x = o[4]; ob.y = o[5]; ob.z = o[6]; ob.w = o[7];
    unsigned short* dst = &y[e0];
    *(ushort4*)dst = oa;
    *(ushort4*)(dst + 4) = ob;
}

// ---------------------------------------------------------------------------
extern "C" void kernel_launch(void* const* d_in, const int* in_sizes, int n_in,
                              void* d_out, int out_size, void* d_ws, size_t ws_size,
                              hipStream_t stream)
{
    const float* x      = (const float*)d_in[0];
    const float* W_attn = (const float*)d_in[1];
    const float* b_attn = (const float*)d_in[2];
    const float* W_proj = (const float*)d_in[3];
    const float* b_proj = (const float*)d_in[4];
    float* out = (float*)d_out;

    char* ws = (char*)d_ws;
    unsigned short* qkv_ws  = (unsigned short*)ws;                    // 37,748,736 B
    float*          lsum_ws = (float*)(ws + 37748736);                //    786,432 B
    unsigned short* x_bf16  = (unsigned short*)(ws + 38535168);       // 12,582,912 B
    unsigned short* wt_attn = (unsigned short*)(ws + 51118080);       //  3,538,944 B
    unsigned short* wt_proj = (unsigned short*)(ws + 54657024);       //  1,179,648 B
    unsigned short* y_part   = (unsigned short*)d_out;                // bf16 [2][8192][768]
    unsigned short* y_merged = x_bf16;   // dead after gemm1

    dim3 blk(256);

    // 0) fused prep: cvt_x + both weight transposes in one dispatch
    prep_kernel<<<dim3(3072 + 432 + 144), blk, 0, stream>>>(
        x, x_bf16, W_attn, wt_attn, W_proj, wt_proj);

    // 1) qkv = x @ W_attn + b_attn  (Q cols pre-scaled by beta) -> bf16
    gemm_bt_kernel<true, true><<<dim3(QKV_ROW / 128, (B_ * T_) / 128), blk, 0, stream>>>(
        x_bf16, wt_attn, b_attn, (void*)qkv_ws, B_ * T_, QKV_ROW, E_, E_);

    // 2) flash attention (XCD-swizzled 1D grid) -> bf16 partials in d_out
    flash_kernel<<<dim3((T_ / 128) * B_ * NH_ * 2), blk, 0, stream>>>(
        qkv_ws, y_part, lsum_ws);

    // 3) merge partials -> contiguous bf16 y
    merge_kernel<<<dim3(BTE / 8 / 256), blk, 0, stream>>>(y_part, lsum_ws, y_merged);

    // 4) out = y @ W_proj + b_proj -> fp32
    gemm_bt_kernel<false, false><<<dim3(E_ / 128, (B_ * T_) / 128), blk, 0, stream>>>(
        y_merged, wt_proj, b_proj, (void*)out, B_ * T_, E_, E_, E_);
}